// Round 1
// baseline (237.827 us; speedup 1.0000x reference)
//
#include <hip/hip_runtime.h>

#define C_IN   128
#define H_IN   56
#define W_IN   56
#define HW     3136      // 56*56
#define CHW    401408    // 128*3136
#define O_OUT  256
#define OHW    802816    // 256*3136

#define BM 256
#define BN 128
#define BK 64
#define LDK 72           // BK + 8 bf16 pad -> 144B row stride, 16B aligned, conflict-free for b128

typedef __bf16 bf16x8 __attribute__((ext_vector_type(8)));
typedef float  f32x4  __attribute__((ext_vector_type(4)));
typedef unsigned short ushort_t;
typedef ushort_t ushort8 __attribute__((ext_vector_type(8)));

__device__ __forceinline__ ushort_t f2bf(float f) {
    union { float f; unsigned u; } v; v.f = f;
    unsigned r = (v.u + 0x7fffu + ((v.u >> 16) & 1u)) >> 16;
    return (ushort_t)r;
}

// Pre-transform weights: w[o][c][kh][kw] fp32 -> wbf[pos][o][c] bf16, pos = kh*3+kw
__global__ void wt_kernel(const float* __restrict__ w, ushort_t* __restrict__ wbf) {
    int idx = blockIdx.x * 256 + threadIdx.x;        // 9*256*128 = 294912
    if (idx >= 9 * 256 * 128) return;
    int pos = idx >> 15;                              // /32768
    int rem = idx & 32767;
    int o   = rem >> 7;
    int c   = rem & 127;
    wbf[idx] = f2bf(w[o * 1152 + c * 9 + pos]);
}

// Implicit-GEMM conv: block computes 256 (o) x 128 (pixels), K loop = 9 pos x 2 halves of 64 ch.
__global__ __launch_bounds__(512, 4)
void conv_kernel(const float* __restrict__ x, const ushort_t* __restrict__ wbf,
                 const float* __restrict__ bias, float* __restrict__ out) {
    __shared__ ushort_t As[BM * LDK];   // 36864 B
    __shared__ ushort_t Bs[BN * LDK];   // 18432 B

    const int tid  = threadIdx.x;
    const int lane = tid & 63;
    const int wave = tid >> 6;     // 0..7
    const int wm   = wave >> 1;    // 0..3 -> 64-row block of the 256 o's
    const int wn   = wave & 1;     // 0..1 -> 64-col block of the 128 pixels
    const int l15  = lane & 15;
    const int quad = lane >> 4;

    const int pix_base = blockIdx.x * BN;

    // B-staging geometry: this thread owns pixel px, channel-groups {cg0, cg0+4}
    const int px  = tid & 127;
    const int cg0 = tid >> 7;                 // 0..3
    const int p   = pix_base + px;
    const int n_img = p / HW;
    const int hw    = p - n_img * HW;
    const int h     = hw / W_IN;
    const int w_    = hw - h * W_IN;
    const float* ximg = x + (long)n_img * CHW;

    f32x4 acc[4][4];
    #pragma unroll
    for (int t = 0; t < 4; ++t)
        #pragma unroll
        for (int u = 0; u < 4; ++u)
            acc[t][u] = f32x4{0.f, 0.f, 0.f, 0.f};

    for (int pos = 0; pos < 9; ++pos) {
        const int dh = pos / 3 - 1;
        const int dw = pos - (pos / 3) * 3 - 1;
        const int ih = h + dh;
        const int iw = w_ + dw;
        const bool valid = ((unsigned)ih < (unsigned)H_IN) && ((unsigned)iw < (unsigned)W_IN);
        const float* xsrc = ximg + ih * W_IN + iw;    // + c*HW added per channel

        for (int half = 0; half < 2; ++half) {
            const int c0 = half * 64;

            // ---- stage A: wbf[pos][o][c0 + cg*8 ..] -> As[o*LDK + cg*8 ..]
            {
                const ushort_t* wsrc = wbf + ((pos * 256) << 7) + c0;
                #pragma unroll
                for (int s = 0; s < 4; ++s) {
                    const int o  = (tid >> 3) + s * 64;
                    const int cg = tid & 7;
                    ushort8 v = *(const ushort8*)(wsrc + (o << 7) + cg * 8);
                    *(ushort8*)(&As[o * LDK + cg * 8]) = v;
                }
            }
            // ---- stage B: x[n][c][ih][iw] (zero-padded) -> Bs[px*LDK + cg*8 ..]
            {
                #pragma unroll
                for (int s = 0; s < 2; ++s) {
                    const int cg = cg0 + s * 4;
                    const float* src = xsrc + (long)(c0 + cg * 8) * HW;
                    ushort8 v;
                    #pragma unroll
                    for (int j = 0; j < 8; ++j) {
                        float f = valid ? src[j * HW] : 0.0f;
                        v[j] = f2bf(f);
                    }
                    *(ushort8*)(&Bs[px * LDK + cg * 8]) = v;
                }
            }
            __syncthreads();

            // ---- compute: 2 k-steps x 16 MFMA
            #pragma unroll
            for (int ks = 0; ks < 2; ++ks) {
                bf16x8 af[4], bfv[4];
                #pragma unroll
                for (int t = 0; t < 4; ++t) {
                    const int row = wm * 64 + t * 16 + l15;
                    af[t] = *(const bf16x8*)(&As[row * LDK + ks * 32 + quad * 8]);
                }
                #pragma unroll
                for (int u = 0; u < 4; ++u) {
                    const int col = wn * 64 + u * 16 + l15;
                    bfv[u] = *(const bf16x8*)(&Bs[col * LDK + ks * 32 + quad * 8]);
                }
                #pragma unroll
                for (int t = 0; t < 4; ++t)
                    #pragma unroll
                    for (int u = 0; u < 4; ++u)
                        acc[t][u] = __builtin_amdgcn_mfma_f32_16x16x32_bf16(af[t], bfv[u], acc[t][u], 0, 0, 0);
            }
            __syncthreads();
        }
    }

    // ---- epilogue: bias add + store. D layout: col = lane&15 (pixel), row = quad*4 + r (o)
    #pragma unroll
    for (int u = 0; u < 4; ++u) {
        const int col = wn * 64 + u * 16 + l15;
        const int pp  = pix_base + col;
        const int nn  = pp / HW;
        const int hw2 = pp - nn * HW;
        const long obase = (long)nn * OHW + hw2;
        #pragma unroll
        for (int t = 0; t < 4; ++t) {
            const int o_base = wm * 64 + t * 16 + quad * 4;
            #pragma unroll
            for (int r = 0; r < 4; ++r) {
                const int o = o_base + r;
                out[obase + (long)o * HW] = acc[t][u][r] + bias[o];
            }
        }
    }
}

extern "C" void kernel_launch(void* const* d_in, const int* in_sizes, int n_in,
                              void* d_out, int out_size, void* d_ws, size_t ws_size,
                              hipStream_t stream) {
    const float* x    = (const float*)d_in[0];
    const float* w    = (const float*)d_in[1];
    const float* bias = (const float*)d_in[2];
    float* out        = (float*)d_out;
    ushort_t* wbf     = (ushort_t*)d_ws;     // 294912 * 2 B = 589824 B

    hipLaunchKernelGGL(wt_kernel, dim3(1152), dim3(256), 0, stream, w, wbf);
    hipLaunchKernelGGL(conv_kernel, dim3(100352 / BN), dim3(512), 0, stream, x, wbf, bias, out);
}